// Round 11
// baseline (148.251 us; speedup 1.0000x reference)
//
#include <hip/hip_runtime.h>
#include <hip/hip_bf16.h>
#include <math.h>

// ---------------------------------------------------------------------------
// SentiGAT — round 10: stage A refactored through weight algebra.
//   S = Xo@(Ws@Wc^T)@zw^T + d_j (+row-const, cancels); aligned = (w16@zw)@Wc+b
//   prep  : vvec, wb=Wc@b, weight transposes, Wc_r, Ws_r
//   ow_zw : per-sample scores/alpha -> zw bf16 [B*16][1024]
//   Pt    : Wc_r @ Ws_r^T           (1024x512x512)
//   Xq    : word @ Pt^T             (6144x1024x512, fp32-A cvt)
//   ow_attn: S=Xq@zw^T+dj -> softmax -> w16 -> y -> Y [B][1024]
//   Ygemm : aligned = Y @ owWt^T + ow_b  (512x512x1024)
//   x5    : ind_norm 5 feats -> x5b
//   C/D   : as round 9
// ---------------------------------------------------------------------------

#define B_SAMP 512

typedef short short8 __attribute__((ext_vector_type(8)));
typedef float floatx4 __attribute__((ext_vector_type(4)));

__device__ __forceinline__ float lrelu02(float x) { return x > 0.f ? x : 0.2f * x; }

__device__ __forceinline__ unsigned short cvt_bf16(float f) {
    union { float f; unsigned int u; } v; v.f = f;
    unsigned int u = v.u;
    return (unsigned short)((u + 0x7FFFu + ((u >> 16) & 1u)) >> 16);  // RNE
}
__device__ __forceinline__ float bf2f(unsigned short u) {
    union { unsigned int u; float f; } v; v.u = ((unsigned int)u) << 16;
    return v.f;
}

// ---------------- prep: vvec + wb + weight transposes + Wc_r + Ws_r ---------
__global__ __launch_bounds__(256) void prep(
    const float* __restrict__ ow_W, const float* __restrict__ ow_asrc,
    const float* __restrict__ ow_adst, const float* __restrict__ ow_b,
    const float* __restrict__ g1_W, const float* __restrict__ g2_W,
    const float* __restrict__ m1_W,
    float* __restrict__ vg, float* __restrict__ wb,
    unsigned short* __restrict__ owWt,
    unsigned short* __restrict__ g1Wt, unsigned short* __restrict__ g2Wt,
    unsigned short* __restrict__ m1Wt,
    unsigned short* __restrict__ WcR, unsigned short* __restrict__ WsR)
{
    __shared__ float T[32][33];
    const int tid = threadIdx.x;
    int bid = blockIdx.x;
    const int lane = tid & 63;
    const int wid = tid >> 6;

    if (bid < 128) {            // vg: 2048 dots of 512
        const int gw = bid * 4 + wid;
        for (int idx = gw; idx < 2048; idx += 512) {
            int t = idx >> 9, k = idx & 511;
            const float* a = (t < 2) ? (ow_asrc + t * 512) : (ow_adst + (t - 2) * 512);
            const float* wr = ow_W + (size_t)k * 1024 + (t & 1) * 512;
            float s = 0.f;
#pragma unroll
            for (int j = 0; j < 8; ++j) s += wr[lane + 64 * j] * a[lane + 64 * j];
            for (int off = 32; off > 0; off >>= 1) s += __shfl_down(s, off, 64);
            if (lane == 0) vg[idx] = s;
        }
        return;
    }
    if (bid < 192) {            // wb[a] = sum_n Wc[a][n]*b[n]
        const int gw = (bid - 128) * 4 + wid;
        for (int a = gw; a < 1024; a += 256) {
            const float* wr = (a < 512) ? (ow_W + (size_t)a * 1024)
                                        : (ow_W + (size_t)(a - 512) * 1024 + 512);
            float s = 0.f;
#pragma unroll
            for (int j = 0; j < 8; ++j) s += wr[lane + 64 * j] * ow_b[lane + 64 * j];
            for (int off = 32; off > 0; off >>= 1) s += __shfl_down(s, off, 64);
            if (lane == 0) wb[a] = 0.5f * s;
        }
        return;
    }
    bid -= 192;
    if (bid >= 2320) {
        int x = bid - 2320;
        if (x < 128) {          // Wc_r[a][n] = 0.5*W[a or a-512][n or n+512]
            int base = x * 4096;
#pragma unroll
            for (int q = 0; q < 4; ++q) {
                int eidx = base + q * 1024 + tid * 4;
                int a = eidx >> 9, n = eidx & 511;
                const float* src = (a < 512) ? (ow_W + (size_t)a * 1024 + n)
                                             : (ow_W + (size_t)(a - 512) * 1024 + 512 + n);
                float4 v = *(const float4*)src;
                ushort4 w;
                w.x = cvt_bf16(0.5f * v.x); w.y = cvt_bf16(0.5f * v.y);
                w.z = cvt_bf16(0.5f * v.z); w.w = cvt_bf16(0.5f * v.w);
                *(ushort4*)(WcR + (size_t)a * 512 + n) = w;
            }
        } else {                // Ws_r[d][n] = 0.5*(W[d][n]+W[d][512+n])
            int base = (x - 128) * 4096;
#pragma unroll
            for (int q = 0; q < 4; ++q) {
                int eidx = base + q * 1024 + tid * 4;
                int d = eidx >> 9, n = eidx & 511;
                float4 v1 = *(const float4*)(ow_W + (size_t)d * 1024 + n);
                float4 v2 = *(const float4*)(ow_W + (size_t)d * 1024 + 512 + n);
                ushort4 w;
                w.x = cvt_bf16(0.5f * (v1.x + v2.x)); w.y = cvt_bf16(0.5f * (v1.y + v2.y));
                w.z = cvt_bf16(0.5f * (v1.z + v2.z)); w.w = cvt_bf16(0.5f * (v1.w + v2.w));
                *(ushort4*)(WsR + (size_t)d * 512 + n) = w;
            }
        }
        return;
    }
    const float* W; int ldw, K, Kpad, koff, ktiles; float scale; unsigned short* Wt;
    if (bid < 256)        { W = ow_W;       ldw = 1024; K = 512;  Kpad = 1024; koff = 0;   scale = 0.5f; Wt = owWt; ktiles = 16; }
    else if (bid < 512)   { bid -= 256;  W = ow_W + 512; ldw = 1024; K = 512;  Kpad = 1024; koff = 512; scale = 0.5f; Wt = owWt; ktiles = 16; }
    else if (bid < 784)   { bid -= 512;  W = g1_W; ldw = 512; K = 513;  Kpad = 544;  koff = 0; scale = 1.f; Wt = g1Wt; ktiles = 17; }
    else if (bid < 1040)  { bid -= 784;  W = g2_W; ldw = 512; K = 512;  Kpad = 512;  koff = 0; scale = 1.f; Wt = g2Wt; ktiles = 16; }
    else                  { bid -= 1040; W = m1_W; ldw = 512; K = 2560; Kpad = 2560; koff = 0; scale = 1.f; Wt = m1Wt; ktiles = 80; }
    const int k0 = (bid % ktiles) * 32;
    const int n0 = (bid / ktiles) * 32;
    {
        int kr = tid >> 3, nc = (tid & 7) * 4;
        float4 v = make_float4(0.f, 0.f, 0.f, 0.f);
        if (k0 + kr < K) v = *(const float4*)(W + (size_t)(k0 + kr) * ldw + n0 + nc);
        T[nc + 0][kr] = v.x * scale; T[nc + 1][kr] = v.y * scale;
        T[nc + 2][kr] = v.z * scale; T[nc + 3][kr] = v.w * scale;
    }
    __syncthreads();
    {
        int nr = tid >> 3, kc = (tid & 7) * 4;
        ushort4 w;
        w.x = cvt_bf16(T[nr][kc + 0]);
        w.y = cvt_bf16(T[nr][kc + 1]);
        w.z = cvt_bf16(T[nr][kc + 2]);
        w.w = cvt_bf16(T[nr][kc + 3]);
        *(ushort4*)(Wt + (size_t)(n0 + nr) * Kpad + koff + k0 + kc) = w;
    }
}

// ---------------- ow_zw: per-sample scores + alpha -> zw bf16 ---------------
__global__ __launch_bounds__(256) void ow_zw(
    const float* __restrict__ wf, const float* __restrict__ of,
    const float* __restrict__ vg,
    unsigned short* __restrict__ zwb)   // [B*16][1024]
{
    const int b = blockIdx.x;
    __shared__ float Xs[28][512];
    __shared__ float ss[28][2], sd[28][2];
    __shared__ float alpha[16][2][13];

    const int tid = threadIdx.x;
    const int lane = tid & 63;
    const int wid = tid >> 6;

    for (int idx = tid; idx < 28 * 128; idx += 256) {
        int n = idx >> 7, c = (idx & 127) * 4;
        const float* src = (n < 12) ? (wf + ((size_t)b * 12 + n) * 512)
                                    : (of + ((size_t)b * 16 + (n - 12)) * 512);
        *(float4*)&Xs[n][c] = *(const float4*)(src + c);
    }
    __syncthreads();

    for (int p = wid; p < 112; p += 4) {
        int n = p >> 2, t = p & 3;
        const float* vv = vg + t * 512;
        float s = 0.f;
#pragma unroll
        for (int j = 0; j < 8; ++j) s += Xs[n][lane + 64 * j] * vv[lane + 64 * j];
        for (int off = 32; off > 0; off >>= 1) s += __shfl_down(s, off, 64);
        if (lane == 0) { if (t < 2) ss[n][t] = s; else sd[n][t - 2] = s; }
    }
    __syncthreads();

    if (tid < 32) {
        int w = tid >> 1, h = tid & 1;
        float sdv = sd[12 + w][h];
        float e[13], mx = -1e30f;
        for (int j = 0; j < 12; ++j) { e[j] = lrelu02(ss[j][h] + sdv); mx = fmaxf(mx, e[j]); }
        e[12] = lrelu02(ss[12 + w][h] + sdv); mx = fmaxf(mx, e[12]);
        float den = 0.f;
        for (int j = 0; j < 13; ++j) { e[j] = expf(e[j] - mx); den += e[j]; }
        float inv = 1.f / den;
        for (int j = 0; j < 13; ++j) alpha[w][h][j] = e[j] * inv;
    }
    __syncthreads();

    unsigned short* zb = zwb + (size_t)b * 16 * 1024;
    for (int c = tid; c < 1024; c += 256) {
        int h = c >> 9, d = c & 511;
        float xr[12];
#pragma unroll
        for (int j = 0; j < 12; ++j) xr[j] = Xs[j][d];
#pragma unroll 4
        for (int w = 0; w < 16; ++w) {
            float a = alpha[w][h][12] * Xs[12 + w][d];
#pragma unroll
            for (int j = 0; j < 12; ++j) a += alpha[w][h][j] * xr[j];
            zb[(size_t)w * 1024 + c] = cvt_bf16(a);
        }
    }
}

// ---------------- gemm_v3: dbuf pipeline; AF32 = fp32-A convert -------------
template <int BM, int BN, int WGM, int RELU, int SPLITK, int OBF16, int AF32>
__global__ __launch_bounds__(256) void gemm_v3(
    const void* __restrict__ Av, int lda,
    const unsigned short* __restrict__ Bt, int ldbt,
    void* __restrict__ Cv, int ldc,
    int M, int N, int K,
    const float* __restrict__ bias)
{
    constexpr int WGN = 4 / WGM;
    constexpr int WM = BM / WGM, WN = BN / WGN;
    constexpr int MF = WM / 16, NF = WN / 16;
    constexpr int CAB = (BM * 4 + 255) / 256;   // bf16-A chunks (short8)
    constexpr int CAF = (BM * 8 + 255) / 256;   // f32-A chunks (float4)
    constexpr int CB  = (BN * 4 + 255) / 256;

    __shared__ unsigned short As[2][BM][40];
    __shared__ unsigned short Bs[2][BN][40];

    const int tid = threadIdx.x;
    const int m0 = blockIdx.x * BM;
    const int n0 = blockIdx.y * BN;
    const int lane = tid & 63;
    const int wid = tid >> 6;
    const int wm = (wid % WGM) * WM;
    const int wn = (wid / WGM) * WN;
    const int fr = lane & 15;
    const int kq = (lane >> 4) * 8;

    const int kchunk = K / SPLITK;
    const int kbeg = (SPLITK > 1) ? blockIdx.z * kchunk : 0;
    const int kend = kbeg + kchunk;
    float* Cf = (float*)Cv;
    unsigned short* Cb = (unsigned short*)Cv;
    if (SPLITK > 1) Cf += (size_t)blockIdx.z * M * ldc;

    short8 ra[CAB]; float4 raf[CAF]; short8 rb[CB];

#define LOADA(K0)                                                                        \
    do {                                                                                 \
        if (AF32) {                                                                      \
            const float* Af = (const float*)Av;                                          \
            _Pragma("unroll")                                                            \
            for (int c = 0; c < CAF; ++c) {                                              \
                int id = tid + c * 256;                                                  \
                raf[c] = *(const float4*)(Af + (size_t)(m0 + (id >> 3)) * lda + (K0) + (id & 7) * 4); \
            }                                                                            \
        } else {                                                                         \
            const unsigned short* Ab = (const unsigned short*)Av;                        \
            _Pragma("unroll")                                                            \
            for (int c = 0; c < CAB; ++c) {                                              \
                int id = tid + c * 256;                                                  \
                if (BM * 4 % 256 == 0 || id < BM * 4)                                    \
                    ra[c] = *(const short8*)(Ab + (size_t)(m0 + (id >> 2)) * lda + (K0) + (id & 3) * 8); \
            }                                                                            \
        }                                                                                \
    } while (0)
#define LOADB(K0)                                                                        \
    do {                                                                                 \
        _Pragma("unroll")                                                                \
        for (int c = 0; c < CB; ++c) {                                                   \
            int id = tid + c * 256;                                                      \
            if (BN * 4 % 256 == 0 || id < BN * 4)                                        \
                rb[c] = *(const short8*)(Bt + (size_t)(n0 + (id >> 2)) * ldbt + (K0) + (id & 3) * 8); \
        }                                                                                \
    } while (0)

    LOADA(kbeg); LOADB(kbeg);

    floatx4 acc[MF][NF];
#pragma unroll
    for (int i = 0; i < MF; ++i)
#pragma unroll
        for (int j = 0; j < NF; ++j) acc[i][j] = (floatx4){0.f, 0.f, 0.f, 0.f};

    int t = 0;
    for (int k0 = kbeg; k0 < kend; k0 += 32, t ^= 1) {
        if (AF32) {
#pragma unroll
            for (int c = 0; c < CAF; ++c) {
                int id = tid + c * 256;
                ushort4 w;
                w.x = cvt_bf16(raf[c].x); w.y = cvt_bf16(raf[c].y);
                w.z = cvt_bf16(raf[c].z); w.w = cvt_bf16(raf[c].w);
                *(ushort4*)&As[t][id >> 3][(id & 7) * 4] = w;
            }
        } else {
#pragma unroll
            for (int c = 0; c < CAB; ++c) {
                int id = tid + c * 256;
                if (BM * 4 % 256 == 0 || id < BM * 4)
                    *(short8*)&As[t][id >> 2][(id & 3) * 8] = ra[c];
            }
        }
#pragma unroll
        for (int c = 0; c < CB; ++c) {
            int id = tid + c * 256;
            if (BN * 4 % 256 == 0 || id < BN * 4)
                *(short8*)&Bs[t][id >> 2][(id & 3) * 8] = rb[c];
        }
        __syncthreads();
        if (k0 + 32 < kend) { LOADA(k0 + 32); LOADB(k0 + 32); }

        short8 af[MF], bw[NF];
#pragma unroll
        for (int i = 0; i < MF; ++i)
            af[i] = *(const short8*)&As[t][wm + i * 16 + fr][kq];
#pragma unroll
        for (int j = 0; j < NF; ++j)
            bw[j] = *(const short8*)&Bs[t][wn + j * 16 + fr][kq];
#pragma unroll
        for (int i = 0; i < MF; ++i)
#pragma unroll
            for (int j = 0; j < NF; ++j)
                acc[i][j] = __builtin_amdgcn_mfma_f32_16x16x32_bf16(
                    af[i], bw[j], acc[i][j], 0, 0, 0);
    }
#undef LOADA
#undef LOADB

    const int fq = lane >> 4;
#pragma unroll
    for (int i = 0; i < MF; ++i) {
#pragma unroll
        for (int j = 0; j < NF; ++j) {
#pragma unroll
            for (int q = 0; q < 4; ++q) {
                int row = m0 + wm + i * 16 + fq * 4 + q;
                int col = n0 + wn + j * 16 + fr;
                float v = acc[i][j][q];
                if (SPLITK == 1 && bias) v += bias[col];
                if (RELU) v = fmaxf(v, 0.f);
                if (OBF16) Cb[(size_t)row * ldc + col] = cvt_bf16(v);
                else       Cf[(size_t)row * ldc + col] = v;
            }
        }
    }
}

// ---------------- ow_attn: S=Xq@zw^T+dj -> softmax -> w16 -> y --------------
__global__ __launch_bounds__(256) void ow_attn(
    const unsigned short* __restrict__ Xq,   // [B*12][1024]
    const unsigned short* __restrict__ zwb,  // [B*16][1024]
    const float* __restrict__ wb,            // [1024]
    unsigned short* __restrict__ Y)          // [B][1024]
{
    const int b = blockIdx.x;
    __shared__ unsigned short xqs[12][1024];
    __shared__ unsigned short zws[16][1024];
    __shared__ float S[12][16];
    __shared__ float dj[16];
    __shared__ float w16[16];

    const int tid = threadIdx.x;
    const int lane = tid & 63;
    const int wid = tid >> 6;

    for (int idx = tid; idx < 12 * 128; idx += 256) {
        int r = idx >> 7, c = (idx & 127) * 8;
        *(short8*)&xqs[r][c] = *(const short8*)(Xq + ((size_t)b * 12 + r) * 1024 + c);
    }
    for (int idx = tid; idx < 16 * 128; idx += 256) {
        int r = idx >> 7, c = (idx & 127) * 8;
        *(short8*)&zws[r][c] = *(const short8*)(zwb + ((size_t)b * 16 + r) * 1024 + c);
    }
    __syncthreads();

    for (int p = wid; p < 208; p += 4) {
        float s = 0.f;
        if (p < 192) {
            int i = p >> 4, j = p & 15;
#pragma unroll
            for (int e = 0; e < 8; ++e) {
                int a = e * 128 + lane * 2;
                unsigned int xv = *(const unsigned int*)&xqs[i][a];
                unsigned int zv = *(const unsigned int*)&zws[j][a];
                s += bf2f((unsigned short)(xv & 0xffff)) * bf2f((unsigned short)(zv & 0xffff))
                   + bf2f((unsigned short)(xv >> 16))    * bf2f((unsigned short)(zv >> 16));
            }
        } else {
            int j = p - 192;
#pragma unroll
            for (int e = 0; e < 8; ++e) {
                int a = e * 128 + lane * 2;
                unsigned int zv = *(const unsigned int*)&zws[j][a];
                s += bf2f((unsigned short)(zv & 0xffff)) * wb[a]
                   + bf2f((unsigned short)(zv >> 16))    * wb[a + 1];
            }
        }
        for (int off = 32; off > 0; off >>= 1) s += __shfl_down(s, off, 64);
        if (lane == 0) { if (p < 192) S[p >> 4][p & 15] = s; else dj[p - 192] = s; }
    }
    __syncthreads();

    if (tid < 12) {
        float mx = -1e30f;
        for (int j = 0; j < 16; ++j) mx = fmaxf(mx, S[tid][j] + dj[j]);
        float den = 0.f;
        for (int j = 0; j < 16; ++j) {
            float p = expf(S[tid][j] + dj[j] - mx);
            S[tid][j] = p; den += p;
        }
        float inv = 1.f / den;
        for (int j = 0; j < 16; ++j) S[tid][j] *= inv;
    }
    __syncthreads();
    if (tid < 16) {
        float s = 0.f;
        for (int i = 0; i < 12; ++i) s += S[i][tid];
        w16[tid] = s * (1.f / 12.f);
    }
    __syncthreads();

    {
        int a0 = tid * 4;
        float acc0 = 0.f, acc1 = 0.f, acc2 = 0.f, acc3 = 0.f;
#pragma unroll
        for (int j = 0; j < 16; ++j) {
            float wj = w16[j];
            ushort4 z4 = *(const ushort4*)&zws[j][a0];
            acc0 += wj * bf2f(z4.x); acc1 += wj * bf2f(z4.y);
            acc2 += wj * bf2f(z4.z); acc3 += wj * bf2f(z4.w);
        }
        ushort4 o;
        o.x = cvt_bf16(acc0); o.y = cvt_bf16(acc1);
        o.z = cvt_bf16(acc2); o.w = cvt_bf16(acc3);
        *(ushort4*)(Y + (size_t)b * 1024 + a0) = o;
    }
}

// ---------------- x5: ind_norm 5 feats -> x5b bf16 (B*5, 544) ---------------
__global__ __launch_bounds__(256) void build_x5(
    const float* __restrict__ t, const float* __restrict__ im,
    const float* __restrict__ it, const float* __restrict__ fa,
    const float* __restrict__ al, unsigned short* __restrict__ x5)
{
    int gw = (int)((blockIdx.x * 256 + threadIdx.x) >> 6);
    int lane = threadIdx.x & 63;
    if (gw >= B_SAMP * 5) return;
    int b = gw / 5, f = gw - b * 5;
    const float* src = (f == 0) ? t : (f == 1) ? im : (f == 2) ? it : (f == 3) ? fa : al;
    src += (size_t)b * 512;

    float vals[8];
    float sum = 0.f, sq = 0.f;
#pragma unroll
    for (int j = 0; j < 8; ++j) {
        float v = src[lane + 64 * j];
        vals[j] = v;
        sum += v;
        sq += v * v;
    }
#pragma unroll
    for (int off = 32; off > 0; off >>= 1) {
        sum += __shfl_xor(sum, off, 64);
        sq  += __shfl_xor(sq,  off, 64);
    }
    float v = (sum != 0.f) ? 1.f : 0.f;
    float nrm = fmaxf(sqrtf(sq + v * v), 1e-12f);
    float inv = 1.f / nrm;
    unsigned short* dst = x5 + (size_t)gw * 544;
#pragma unroll
    for (int j = 0; j < 8; ++j) dst[lane + 64 * j] = cvt_bf16(vals[j] * inv);
    if (lane == 0) dst[512] = cvt_bf16(v * inv);
    else if (lane < 32) dst[512 + lane] = 0;
}

// ---------------- C2/C4: 5-node complete-graph GAT (bf16 in/out) ------------
template <int RELU>
__global__ __launch_bounds__(256) void g5_gat(
    const unsigned short* __restrict__ Hg,
    const float* __restrict__ asrc, const float* __restrict__ adst,
    const float* __restrict__ bias, unsigned short* __restrict__ outp)
{
    const int b = blockIdx.x;
    __shared__ float ss[5], sd[5];
    __shared__ float alpha[5][5];

    const int tid = threadIdx.x;
    const int lane = tid & 63;
    const int wave = tid >> 6;
    const unsigned short* Hb = Hg + (size_t)b * 5 * 512;

    for (int p = wave; p < 10; p += 4) {
        int n = p >> 1, ty = p & 1;
        const unsigned short* hv = Hb + n * 512;
        const float* av = ty ? adst : asrc;
        float s = 0.f;
#pragma unroll
        for (int j = 0; j < 8; ++j) s += bf2f(hv[lane + 64 * j]) * av[lane + 64 * j];
        for (int off = 32; off > 0; off >>= 1) s += __shfl_down(s, off, 64);
        if (lane == 0) { if (ty) sd[n] = s; else ss[n] = s; }
    }
    __syncthreads();

    if (tid < 5) {
        int dn = tid;
        float e[5];
        float mx = -1e30f;
        for (int s = 0; s < 5; ++s) {
            e[s] = lrelu02(ss[s] + sd[dn]);
            mx = fmaxf(mx, e[s]);
        }
        float den = 0.f;
        for (int s = 0; s < 5; ++s) { e[s] = expf(e[s] - mx); den += e[s]; }
        float inv = 1.f / den;
        for (int s = 0; s < 5; ++s) alpha[dn][s] = e[s] * inv;
    }
    __syncthreads();

    for (int d = tid; d < 512; d += 256) {
        float h0 = bf2f(Hb[0 * 512 + d]), h1 = bf2f(Hb[1 * 512 + d]), h2 = bf2f(Hb[2 * 512 + d]);
        float h3 = bf2f(Hb[3 * 512 + d]), h4 = bf2f(Hb[4 * 512 + d]);
        float bd = bias[d];
#pragma unroll
        for (int dn = 0; dn < 5; ++dn) {
            float v = alpha[dn][0] * h0 + alpha[dn][1] * h1 + alpha[dn][2] * h2 +
                      alpha[dn][3] * h3 + alpha[dn][4] * h4 + bd;
            if (RELU) v = fmaxf(v, 0.f);
            outp[((size_t)b * 5 + dn) * 512 + d] = cvt_bf16(v);
        }
    }
}

// ---------------- final: relu(sum split-K parts + b1) @ m2 + b2 -------------
__global__ __launch_bounds__(64) void final2(
    const float* __restrict__ parts, const float* __restrict__ b1,
    const float* __restrict__ w, const float* __restrict__ bvec,
    float* __restrict__ out)
{
    const int b = blockIdx.x;
    const int lane = threadIdx.x;
    float a0 = 0.f, a1 = 0.f, a2 = 0.f;
#pragma unroll
    for (int j = 0; j < 8; ++j) {
        int d = lane + 64 * j;
        size_t o = (size_t)b * 512 + d;
        float x = parts[o] + parts[262144 + o] + parts[524288 + o] + parts[786432 + o] + b1[d];
        x = fmaxf(x, 0.f);
        a0 += x * w[d * 3 + 0];
        a1 += x * w[d * 3 + 1];
        a2 += x * w[d * 3 + 2];
    }
    for (int off = 32; off > 0; off >>= 1) {
        a0 += __shfl_down(a0, off, 64);
        a1 += __shfl_down(a1, off, 64);
        a2 += __shfl_down(a2, off, 64);
    }
    if (lane == 0) {
        out[b * 3 + 0] = a0 + bvec[0];
        out[b * 3 + 1] = a1 + bvec[1];
        out[b * 3 + 2] = a2 + bvec[2];
    }
}

extern "C" void kernel_launch(void* const* d_in, const int* in_sizes, int n_in,
                              void* d_out, int out_size, void* d_ws, size_t ws_size,
                              hipStream_t stream) {
    const float* text   = (const float*)d_in[0];
    const float* image  = (const float*)d_in[1];
    const float* imgtxt = (const float*)d_in[2];
    const float* face   = (const float*)d_in[3];
    const float* word   = (const float*)d_in[4];
    const float* obj    = (const float*)d_in[5];
    const float* ow_W    = (const float*)d_in[6];
    const float* ow_asrc = (const float*)d_in[7];
    const float* ow_adst = (const float*)d_in[8];
    const float* ow_b    = (const float*)d_in[9];
    const float* g1_W    = (const float*)d_in[10];
    const float* g1_asrc = (const float*)d_in[11];
    const float* g1_adst = (const float*)d_in[12];
    const float* g1_b    = (const float*)d_in[13];
    const float* g2_W    = (const float*)d_in[14];
    const float* g2_asrc = (const float*)d_in[15];
    const float* g2_adst = (const float*)d_in[16];
    const float* g2_b    = (const float*)d_in[17];
    const float* m1_W    = (const float*)d_in[18];
    const float* m1_b    = (const float*)d_in[19];
    const float* m2_W    = (const float*)d_in[20];
    const float* m2_b    = (const float*)d_in[21];

    float* ws = (float*)d_ws;
    float* vg      = ws;                       // 2048
    float* wb      = ws + 2048;                // 1024
    float* hidp    = ws + 3072;                // 1,048,576
    float* aligned = hidp + 1048576;           // 262,144
    unsigned short* owWt = (unsigned short*)(aligned + 262144);  // 512x1024
    unsigned short* WcR  = owWt + 524288;      // 1024x512
    unsigned short* WsR  = WcR + 524288;       // 512x512
    unsigned short* Pt   = WsR + 262144;       // 1024x512
    unsigned short* g1Wt = Pt + 524288;        // 512x544
    unsigned short* g2Wt = g1Wt + 278528;      // 512x512
    unsigned short* m1Wt = g2Wt + 262144;      // 512x2560
    unsigned short* Xq   = m1Wt + 1310720;     // 6144x1024
    unsigned short* zwb  = Xq + 6291456;       // 8192x1024
    unsigned short* Yb   = zwb + 8388608;      // 512x1024
    unsigned short* x5b  = Yb + 524288;        // 2560x544
    unsigned short* h1b  = x5b + 1392640;      // 2560x512
    unsigned short* fsb  = h1b + 1310720;      // 2560x512
    unsigned short* hgb  = fsb + 1310720;      // 2560x512

    // prep
    prep<<<2704, 256, 0, stream>>>(ow_W, ow_asrc, ow_adst, ow_b, g1_W, g2_W, m1_W,
                                   vg, wb, owWt, g1Wt, g2Wt, m1Wt, WcR, WsR);

    // stage A (factored)
    ow_zw<<<B_SAMP, 256, 0, stream>>>(word, obj, vg, zwb);
    gemm_v3<64, 64, 2, 0, 1, 1, 0><<<dim3(16, 8), 256, 0, stream>>>(
        WcR, 512, WsR, 512, Pt, 512, 1024, 512, 512, nullptr);
    gemm_v3<64, 128, 2, 0, 1, 1, 1><<<dim3(96, 8), 256, 0, stream>>>(
        word, 512, Pt, 512, Xq, 1024, 6144, 1024, 512, nullptr);
    ow_attn<<<B_SAMP, 256, 0, stream>>>(Xq, zwb, wb, Yb);
    gemm_v3<64, 64, 2, 0, 1, 0, 0><<<dim3(8, 8), 256, 0, stream>>>(
        Yb, 1024, owWt, 1024, aligned, 512, 512, 512, 1024, ow_b);
    build_x5<<<640, 256, 0, stream>>>(text, image, imgtxt, face, aligned, x5b);

    // stage C
    gemm_v3<64, 64, 2, 0, 1, 1, 0><<<dim3(40, 8), 256, 0, stream>>>(
        x5b, 544, g1Wt, 544, hgb, 512, 2560, 512, 544, nullptr);
    g5_gat<1><<<B_SAMP, 256, 0, stream>>>(hgb, g1_asrc, g1_adst, g1_b, h1b);
    gemm_v3<64, 64, 2, 0, 1, 1, 0><<<dim3(40, 8), 256, 0, stream>>>(
        h1b, 512, g2Wt, 512, hgb, 512, 2560, 512, 512, nullptr);
    g5_gat<0><<<B_SAMP, 256, 0, stream>>>(hgb, g2_asrc, g2_adst, g2_b, fsb);

    // stage D
    gemm_v3<64, 64, 2, 0, 4, 0, 0><<<dim3(8, 8, 4), 256, 0, stream>>>(
        fsb, 2560, m1Wt, 2560, hidp, 512, 512, 512, 2560, nullptr);
    final2<<<B_SAMP, 64, 0, stream>>>(hidp, m1_b, m2_W, m2_b, (float*)d_out);
}

// Round 13
// 131.499 us; speedup vs baseline: 1.1274x; 1.1274x over previous
//
#include <hip/hip_runtime.h>
#include <hip/hip_bf16.h>
#include <math.h>

// ---------------------------------------------------------------------------
// SentiGAT — round 12: round-11 structure with the WsR transpose bug fixed
// (WsR now goes through the generic LDS-transpose path with sum-halves mode,
// producing proper [N][K] layout).
// ---------------------------------------------------------------------------

#define B_SAMP 512

typedef short short8 __attribute__((ext_vector_type(8)));
typedef float floatx4 __attribute__((ext_vector_type(4)));

__device__ __forceinline__ float lrelu02(float x) { return x > 0.f ? x : 0.2f * x; }

__device__ __forceinline__ unsigned short cvt_bf16(float f) {
    union { float f; unsigned int u; } v; v.f = f;
    unsigned int u = v.u;
    return (unsigned short)((u + 0x7FFFu + ((u >> 16) & 1u)) >> 16);  // RNE
}
__device__ __forceinline__ float bf2f(unsigned short u) {
    union { unsigned int u; float f; } v; v.u = ((unsigned int)u) << 16;
    return v.f;
}
__device__ __forceinline__ void gload_lds16(const unsigned short* g, unsigned short* l) {
    __builtin_amdgcn_global_load_lds(
        (const __attribute__((address_space(1))) void*)g,
        (__attribute__((address_space(3))) void*)l, 16, 0, 0);
}

// ---------------- prep: vg + weight transposes (incl. WsR sum-halves) -------
__global__ __launch_bounds__(256) void prep(
    const float* __restrict__ ow_W, const float* __restrict__ ow_asrc,
    const float* __restrict__ ow_adst,
    const float* __restrict__ g1_W, const float* __restrict__ g2_W,
    const float* __restrict__ m1_W,
    float* __restrict__ vg, unsigned short* __restrict__ owWt,
    unsigned short* __restrict__ g1Wt, unsigned short* __restrict__ g2Wt,
    unsigned short* __restrict__ m1Wt, unsigned short* __restrict__ WsR)
{
    __shared__ float T[32][33];
    const int tid = threadIdx.x;
    int bid = blockIdx.x;
    const int lane = tid & 63;
    const int wid = tid >> 6;

    if (bid < 128) {            // vg: 2048 dots of 512
        const int gw = bid * 4 + wid;
        for (int idx = gw; idx < 2048; idx += 512) {
            int t = idx >> 9, k = idx & 511;
            const float* a = (t < 2) ? (ow_asrc + t * 512) : (ow_adst + (t - 2) * 512);
            const float* wr = ow_W + (size_t)k * 1024 + (t & 1) * 512;
            float s = 0.f;
#pragma unroll
            for (int j = 0; j < 8; ++j) s += wr[lane + 64 * j] * a[lane + 64 * j];
            for (int off = 32; off > 0; off >>= 1) s += __shfl_down(s, off, 64);
            if (lane == 0) vg[idx] = s;
        }
        return;
    }
    bid -= 128;
    const float* W; int ldw, K, Kpad, koff, ktiles; float scale; unsigned short* Wt;
    int sumh = 0;
    if (bid < 256)        { W = ow_W;       ldw = 1024; K = 512;  Kpad = 1024; koff = 0;   scale = 0.5f; Wt = owWt; ktiles = 16; }
    else if (bid < 512)   { bid -= 256;  W = ow_W + 512; ldw = 1024; K = 512;  Kpad = 1024; koff = 512; scale = 0.5f; Wt = owWt; ktiles = 16; }
    else if (bid < 784)   { bid -= 512;  W = g1_W; ldw = 512; K = 513;  Kpad = 544;  koff = 0; scale = 1.f; Wt = g1Wt; ktiles = 17; }
    else if (bid < 1040)  { bid -= 784;  W = g2_W; ldw = 512; K = 512;  Kpad = 512;  koff = 0; scale = 1.f; Wt = g2Wt; ktiles = 16; }
    else if (bid < 2320)  { bid -= 1040; W = m1_W; ldw = 512; K = 2560; Kpad = 2560; koff = 0; scale = 1.f; Wt = m1Wt; ktiles = 80; }
    else                  { bid -= 2320; W = ow_W; ldw = 1024; K = 512; Kpad = 512; koff = 0; scale = 0.5f; Wt = WsR; ktiles = 16; sumh = 1; }
    const int k0 = (bid % ktiles) * 32;
    const int n0 = (bid / ktiles) * 32;
    {
        int kr = tid >> 3, nc = (tid & 7) * 4;
        float4 v = make_float4(0.f, 0.f, 0.f, 0.f);
        if (k0 + kr < K) {
            v = *(const float4*)(W + (size_t)(k0 + kr) * ldw + n0 + nc);
            if (sumh) {
                float4 v2 = *(const float4*)(W + (size_t)(k0 + kr) * ldw + 512 + n0 + nc);
                v.x += v2.x; v.y += v2.y; v.z += v2.z; v.w += v2.w;
            }
        }
        T[nc + 0][kr] = v.x * scale; T[nc + 1][kr] = v.y * scale;
        T[nc + 2][kr] = v.z * scale; T[nc + 3][kr] = v.w * scale;
    }
    __syncthreads();
    {
        int nr = tid >> 3, kc = (tid & 7) * 4;
        ushort4 w;
        w.x = cvt_bf16(T[nr][kc + 0]);
        w.y = cvt_bf16(T[nr][kc + 1]);
        w.z = cvt_bf16(T[nr][kc + 2]);
        w.w = cvt_bf16(T[nr][kc + 3]);
        *(ushort4*)(Wt + (size_t)(n0 + nr) * Kpad + koff + k0 + kc) = w;
    }
}

// ---------------- ow_zw: scores + alpha -> zw (word rows only) --------------
__global__ __launch_bounds__(256) void ow_zw(
    const float* __restrict__ wf, const float* __restrict__ of,
    const float* __restrict__ vg,
    unsigned short* __restrict__ zw)   // [B*16][1024]
{
    const int b = blockIdx.x;
    __shared__ float Xs[28][512];
    __shared__ float ss[28][2], sd[28][2];
    __shared__ float alpha[16][2][13];

    const int tid = threadIdx.x;
    const int lane = tid & 63;
    const int wid = tid >> 6;

    for (int idx = tid; idx < 28 * 128; idx += 256) {
        int n = idx >> 7, c = (idx & 127) * 4;
        const float* src = (n < 12) ? (wf + ((size_t)b * 12 + n) * 512)
                                    : (of + ((size_t)b * 16 + (n - 12)) * 512);
        *(float4*)&Xs[n][c] = *(const float4*)(src + c);
    }
    __syncthreads();

    for (int p = wid; p < 112; p += 4) {
        int n = p >> 2, t = p & 3;
        const float* vv = vg + t * 512;
        float s = 0.f;
#pragma unroll
        for (int j = 0; j < 8; ++j) s += Xs[n][lane + 64 * j] * vv[lane + 64 * j];
        for (int off = 32; off > 0; off >>= 1) s += __shfl_down(s, off, 64);
        if (lane == 0) { if (t < 2) ss[n][t] = s; else sd[n][t - 2] = s; }
    }
    __syncthreads();

    if (tid < 32) {
        int w = tid >> 1, h = tid & 1;
        float sdv = sd[12 + w][h];
        float e[13], mx = -1e30f;
        for (int j = 0; j < 12; ++j) { e[j] = lrelu02(ss[j][h] + sdv); mx = fmaxf(mx, e[j]); }
        e[12] = lrelu02(ss[12 + w][h] + sdv); mx = fmaxf(mx, e[12]);
        float den = 0.f;
        for (int j = 0; j < 13; ++j) { e[j] = expf(e[j] - mx); den += e[j]; }
        float inv = 1.f / den;
        for (int j = 0; j < 13; ++j) alpha[w][h][j] = e[j] * inv;
    }
    __syncthreads();

    const int c4 = tid * 4;
    const int h = tid >> 7;
    const int d = c4 & 511;
    float4 xr[12];
#pragma unroll
    for (int j = 0; j < 12; ++j) xr[j] = *(const float4*)&Xs[j][d];
    unsigned short* zb = zw + (size_t)b * 16 * 1024;
#pragma unroll 4
    for (int w = 0; w < 16; ++w) {
        const float* al = &alpha[w][h][0];
        float4 xw = *(const float4*)&Xs[12 + w][d];
        float a0 = al[12] * xw.x, a1 = al[12] * xw.y, a2 = al[12] * xw.z, a3 = al[12] * xw.w;
#pragma unroll
        for (int j = 0; j < 12; ++j) {
            a0 += al[j] * xr[j].x; a1 += al[j] * xr[j].y;
            a2 += al[j] * xr[j].z; a3 += al[j] * xr[j].w;
        }
        ushort4 o;
        o.x = cvt_bf16(a0); o.y = cvt_bf16(a1); o.z = cvt_bf16(a2); o.w = cvt_bf16(a3);
        *(ushort4*)(zb + (size_t)w * 1024 + c4) = o;
    }
}

// ---------------- gemm_a1: dual GEMM (houtW glds | houtO fp32-cvt) ----------
__global__ __launch_bounds__(256) void gemm_a1(
    const unsigned short* __restrict__ zw,    // [8192][1024]
    const unsigned short* __restrict__ owWt,  // [512][1024]
    const float* __restrict__ word,           // [6144][512]
    const unsigned short* __restrict__ WsR,   // [512][512]  ([N][K])
    const float* __restrict__ bias,
    unsigned short* __restrict__ houtW,       // [8192][512]
    unsigned short* __restrict__ houtO)       // [6144][512]
{
    __shared__ unsigned short As[2][64][32];
    __shared__ unsigned short Bs[2][128][32];

    const int tid = threadIdx.x;
    const int lane = tid & 63;
    const int wid = tid >> 6;
    const int bid = blockIdx.x;

    const int wm = (wid & 1) * 32;
    const int wn = (wid >> 1) * 64;
    const int fr = lane & 15;
    const int kq = (lane >> 4) * 8;
    const int fq = lane >> 4;

    floatx4 acc[2][4];
#pragma unroll
    for (int i = 0; i < 2; ++i)
#pragma unroll
        for (int j = 0; j < 4; ++j) acc[i][j] = (floatx4){0.f, 0.f, 0.f, 0.f};

    if (bid < 512) {
        // ---- part W: houtW = zw @ owWt^T + b  (K=1024, glds staging) ----
        const int m0 = (bid & 127) * 64;
        const int n0 = (bid >> 7) * 128;
        const int srow = lane >> 2;
        const int sseg = (lane & 3) * 8;
        const unsigned short* ga = zw + (size_t)(m0 + wid * 16 + srow) * 1024 + sseg;
        const unsigned short* gb = owWt + (size_t)(n0 + wid * 32 + srow) * 1024 + sseg;
        const size_t b16 = (size_t)16 * 1024;

#define STAGEW(t, K0)                                             \
    do {                                                          \
        gload_lds16(ga + (K0), &As[t][wid * 16][0]);              \
        gload_lds16(gb + (K0), &Bs[t][wid * 32][0]);              \
        gload_lds16(gb + (K0) + b16, &Bs[t][wid * 32 + 16][0]);   \
    } while (0)

        STAGEW(0, 0);
        __syncthreads();
        int t = 0;
        for (int k0 = 0; k0 < 1024; k0 += 32, t ^= 1) {
            if (k0 + 32 < 1024) STAGEW(t ^ 1, k0 + 32);
            short8 af[2], bw[4];
#pragma unroll
            for (int i = 0; i < 2; ++i)
                af[i] = *(const short8*)&As[t][wm + i * 16 + fr][kq];
#pragma unroll
            for (int j = 0; j < 4; ++j)
                bw[j] = *(const short8*)&Bs[t][wn + j * 16 + fr][kq];
#pragma unroll
            for (int i = 0; i < 2; ++i)
#pragma unroll
                for (int j = 0; j < 4; ++j)
                    acc[i][j] = __builtin_amdgcn_mfma_f32_16x16x32_bf16(
                        af[i], bw[j], acc[i][j], 0, 0, 0);
            __syncthreads();
        }
#undef STAGEW
#pragma unroll
        for (int i = 0; i < 2; ++i)
#pragma unroll
            for (int j = 0; j < 4; ++j)
#pragma unroll
                for (int q = 0; q < 4; ++q) {
                    int row = m0 + wm + i * 16 + fq * 4 + q;
                    int col = n0 + wn + j * 16 + fr;
                    houtW[(size_t)row * 512 + col] = cvt_bf16(acc[i][j][q] + bias[col]);
                }
    } else {
        // ---- part O: houtO = word @ WsR^T + b  (K=512, fp32-A cvt staging) ----
        const int tb = bid - 512;
        const int m0 = (tb % 96) * 64;
        const int n0 = (tb / 96) * 128;

        float4 raf[2]; short8 rb[2];
#define LOADO(K0)                                                                  \
    do {                                                                           \
        _Pragma("unroll")                                                          \
        for (int c = 0; c < 2; ++c) {                                              \
            int id = tid + c * 256;                                                \
            raf[c] = *(const float4*)(word + (size_t)(m0 + (id >> 3)) * 512 + (K0) + (id & 7) * 4); \
            rb[c]  = *(const short8*)(WsR + (size_t)(n0 + (id >> 2)) * 512 + (K0) + (id & 3) * 8);  \
        }                                                                          \
    } while (0)

        LOADO(0);
        int t = 0;
        for (int k0 = 0; k0 < 512; k0 += 32, t ^= 1) {
#pragma unroll
            for (int c = 0; c < 2; ++c) {
                int id = tid + c * 256;
                ushort4 w;
                w.x = cvt_bf16(raf[c].x); w.y = cvt_bf16(raf[c].y);
                w.z = cvt_bf16(raf[c].z); w.w = cvt_bf16(raf[c].w);
                *(ushort4*)&As[t][id >> 3][(id & 7) * 4] = w;
                *(short8*)&Bs[t][id >> 2][(id & 3) * 8] = rb[c];
            }
            __syncthreads();
            if (k0 + 32 < 512) LOADO(k0 + 32);
            short8 af[2], bw[4];
#pragma unroll
            for (int i = 0; i < 2; ++i)
                af[i] = *(const short8*)&As[t][wm + i * 16 + fr][kq];
#pragma unroll
            for (int j = 0; j < 4; ++j)
                bw[j] = *(const short8*)&Bs[t][wn + j * 16 + fr][kq];
#pragma unroll
            for (int i = 0; i < 2; ++i)
#pragma unroll
                for (int j = 0; j < 4; ++j)
                    acc[i][j] = __builtin_amdgcn_mfma_f32_16x16x32_bf16(
                        af[i], bw[j], acc[i][j], 0, 0, 0);
        }
#undef LOADO
#pragma unroll
        for (int i = 0; i < 2; ++i)
#pragma unroll
            for (int j = 0; j < 4; ++j)
#pragma unroll
                for (int q = 0; q < 4; ++q) {
                    int row = m0 + wm + i * 16 + fq * 4 + q;
                    int col = n0 + wn + j * 16 + fr;
                    houtO[(size_t)row * 512 + col] = cvt_bf16(acc[i][j][q] + bias[col]);
                }
    }
}

// ---------------- attn + ind_norm fused ------------------------------------
__global__ __launch_bounds__(256) void attn_x5(
    const unsigned short* __restrict__ houtO,
    const unsigned short* __restrict__ houtW,
    const float* __restrict__ tf, const float* __restrict__ im,
    const float* __restrict__ it, const float* __restrict__ fa,
    unsigned short* __restrict__ x5)
{
    const int b = blockIdx.x;
    __shared__ float uo[12][520];
    __shared__ float uw[16][520];
    __shared__ float S[12][16];
    __shared__ float w16[16];
    __shared__ float al[512];

    const int tid = threadIdx.x;
    const int lane = tid & 63;
    const int wid = tid >> 6;
    const unsigned short* ho = houtO + (size_t)b * 12 * 512;
    const unsigned short* hw = houtW + (size_t)b * 16 * 512;

    for (int idx = tid; idx < 28 * 64; idx += 256) {
        int n = idx >> 6, c = (idx & 63) * 8;
        const unsigned short* src = (n < 12) ? (ho + (size_t)n * 512 + c)
                                             : (hw + (size_t)(n - 12) * 512 + c);
        short8 v = *(const short8*)src;
        float* row = (n < 12) ? &uo[n][c] : &uw[n - 12][c];
#pragma unroll
        for (int j = 0; j < 8; ++j) row[j] = bf2f((unsigned short)v[j]);
    }
    __syncthreads();

    for (int p = wid; p < 192; p += 4) {
        int i = p >> 4, j = p & 15;
        const float* ua = &uo[i][lane * 8];
        const float* uc = &uw[j][lane * 8];
        float s = 0.f;
#pragma unroll
        for (int d = 0; d < 8; ++d) s += ua[d] * uc[d];
        for (int off = 32; off > 0; off >>= 1) s += __shfl_down(s, off, 64);
        if (lane == 0) S[i][j] = s;
    }
    __syncthreads();

    if (tid < 12) {
        float mx = -1e30f;
        for (int j = 0; j < 16; ++j) mx = fmaxf(mx, S[tid][j]);
        float den = 0.f;
        for (int j = 0; j < 16; ++j) { float p = expf(S[tid][j] - mx); S[tid][j] = p; den += p; }
        float inv = 1.f / den;
        for (int j = 0; j < 16; ++j) S[tid][j] *= inv;
    }
    __syncthreads();

    if (tid < 16) {
        float s = 0.f;
        for (int i = 0; i < 12; ++i) s += S[i][tid];
        w16[tid] = s * (1.f / 12.f);
    }
    __syncthreads();

    for (int d = tid; d < 512; d += 256) {
        float s = 0.f;
#pragma unroll
        for (int j = 0; j < 16; ++j) s += w16[j] * uw[j][d];
        al[d] = s;
    }
    __syncthreads();

    for (int f = wid; f < 5; f += 4) {
        const float* src = (f == 0) ? tf : (f == 1) ? im : (f == 2) ? it : (f == 3) ? fa : nullptr;
        float vals[8];
        float sum = 0.f, sq = 0.f;
#pragma unroll
        for (int j = 0; j < 8; ++j) {
            float v = (f < 4) ? src[(size_t)b * 512 + lane + 64 * j] : al[lane + 64 * j];
            vals[j] = v;
            sum += v;
            sq += v * v;
        }
#pragma unroll
        for (int off = 32; off > 0; off >>= 1) {
            sum += __shfl_xor(sum, off, 64);
            sq  += __shfl_xor(sq,  off, 64);
        }
        float v = (sum != 0.f) ? 1.f : 0.f;
        float nrm = fmaxf(sqrtf(sq + v * v), 1e-12f);
        float inv = 1.f / nrm;
        unsigned short* dst = x5 + ((size_t)b * 5 + f) * 544;
#pragma unroll
        for (int j = 0; j < 8; ++j) dst[lane + 64 * j] = cvt_bf16(vals[j] * inv);
        if (lane == 0) dst[512] = cvt_bf16(v * inv);
        else if (lane < 32) dst[512 + lane] = 0;
    }
}

// ---------------- GEMM v3: dbuf pipeline (reg-staged), 64x64 ----------------
template <int BM, int BN, int WGM, int RELU, int SPLITK, int OBF16>
__global__ __launch_bounds__(256) void gemm_v3(
    const unsigned short* __restrict__ A, int lda,
    const unsigned short* __restrict__ Bt, int ldbt,
    void* __restrict__ Cv, int ldc,
    int M, int N, int K,
    const float* __restrict__ bias)
{
    constexpr int WGN = 4 / WGM;
    constexpr int WM = BM / WGM, WN = BN / WGN;
    constexpr int MF = WM / 16, NF = WN / 16;
    constexpr int CA = (BM * 4 + 255) / 256, CB = (BN * 4 + 255) / 256;

    __shared__ unsigned short As[2][BM][40];
    __shared__ unsigned short Bs[2][BN][40];

    const int tid = threadIdx.x;
    const int m0 = blockIdx.x * BM;
    const int n0 = blockIdx.y * BN;
    const int lane = tid & 63;
    const int wid = tid >> 6;
    const int wm = (wid % WGM) * WM;
    const int wn = (wid / WGM) * WN;
    const int fr = lane & 15;
    const int kq = (lane >> 4) * 8;

    const int kchunk = K / SPLITK;
    const int kbeg = (SPLITK > 1) ? blockIdx.z * kchunk : 0;
    const int kend = kbeg + kchunk;
    float* Cf = (float*)Cv;
    unsigned short* Cb = (unsigned short*)Cv;
    if (SPLITK > 1) Cf += (size_t)blockIdx.z * M * ldc;

    short8 ra[CA], rb[CB];
#define LOADAB(K0)                                                                       \
    do {                                                                                 \
        _Pragma("unroll")                                                                \
        for (int c = 0; c < CA; ++c) {                                                   \
            int id = tid + c * 256;                                                      \
            if (BM * 4 % 256 == 0 || id < BM * 4)                                        \
                ra[c] = *(const short8*)(A + (size_t)(m0 + (id >> 2)) * lda + (K0) + (id & 3) * 8); \
        }                                                                                \
        _Pragma("unroll")                                                                \
        for (int c = 0; c < CB; ++c) {                                                   \
            int id = tid + c * 256;                                                      \
            if (BN * 4 % 256 == 0 || id < BN * 4)                                        \
                rb[c] = *(const short8*)(Bt + (size_t)(n0 + (id >> 2)) * ldbt + (K0) + (id & 3) * 8); \
        }                                                                                \
    } while (0)

    LOADAB(kbeg);

    floatx4 acc[MF][NF];
#pragma unroll
    for (int i = 0; i < MF; ++i)
#pragma unroll
        for (int j = 0; j < NF; ++j) acc[i][j] = (floatx4){0.f, 0.f, 0.f, 0.f};

    int t = 0;
    for (int k0 = kbeg; k0 < kend; k0 += 32, t ^= 1) {
#pragma unroll
        for (int c = 0; c < CA; ++c) {
            int id = tid + c * 256;
            if (BM * 4 % 256 == 0 || id < BM * 4)
                *(short8*)&As[t][id >> 2][(id & 3) * 8] = ra[c];
        }
#pragma unroll
        for (int c = 0; c < CB; ++c) {
            int id = tid + c * 256;
            if (BN * 4 % 256 == 0 || id < BN * 4)
                *(short8*)&Bs[t][id >> 2][(id & 3) * 8] = rb[c];
        }
        __syncthreads();
        if (k0 + 32 < kend) LOADAB(k0 + 32);

        short8 af[MF], bw[NF];
#pragma unroll
        for (int i = 0; i < MF; ++i)
            af[i] = *(const short8*)&As[t][wm + i * 16 + fr][kq];
#pragma unroll
        for (int j = 0; j < NF; ++j)
            bw[j] = *(const short8*)&Bs[t][wn + j * 16 + fr][kq];
#pragma unroll
        for (int i = 0; i < MF; ++i)
#pragma unroll
            for (int j = 0; j < NF; ++j)
                acc[i][j] = __builtin_amdgcn_mfma_f32_16x16x32_bf16(
                    af[i], bw[j], acc[i][j], 0, 0, 0);
    }
#undef LOADAB

    const int fq = lane >> 4;
#pragma unroll
    for (int i = 0; i < MF; ++i) {
#pragma unroll
        for (int j = 0; j < NF; ++j) {
#pragma unroll
            for (int q = 0; q < 4; ++q) {
                int row = m0 + wm + i * 16 + fq * 4 + q;
                int col = n0 + wn + j * 16 + fr;
                float v = acc[i][j][q];
                if (SPLITK == 1 && bias) v += bias[col];
                if (RELU) v = fmaxf(v, 0.f);
                if (OBF16) Cb[(size_t)row * ldc + col] = cvt_bf16(v);
                else       Cf[(size_t)row * ldc + col] = v;
            }
        }
    }
}

// ---------------- C2/C4: 5-node complete-graph GAT (bf16 in/out) ------------
template <int RELU>
__global__ __launch_bounds__(256) void g5_gat(
    const unsigned short* __restrict__ Hg,
    const float* __restrict__ asrc, const float* __restrict__ adst,
    const float* __restrict__ bias, unsigned short* __restrict__ outp)
{
    const int b = blockIdx.x;
    __shared__ float ss[5], sd[5];
    __shared__ float alpha[5][5];

    const int tid = threadIdx.x;
    const int lane = tid & 63;
    const int wave = tid >> 6;
    const unsigned short* Hb = Hg + (size_t)b * 5 * 512;

    for (int p = wave; p < 10; p += 4) {
        int n = p >> 1, ty = p & 1;
        const unsigned short* hv = Hb + n * 512;
        const float* av = ty ? adst : asrc;
        float s = 0.f;
#pragma unroll
        for (int j = 0; j < 8; ++j) s += bf2f(hv[lane + 64 * j]) * av[lane + 64 * j];
        for (int off = 32; off > 0; off >>= 1) s += __shfl_down(s, off, 64);
        if (lane == 0) { if (ty) sd[n] = s; else ss[n] = s; }
    }
    __syncthreads();

    if (tid < 5) {
        int dn = tid;
        float e[5];
        float mx = -1e30f;
        for (int s = 0; s < 5; ++s) {
            e[s] = lrelu02(ss[s] + sd[dn]);
            mx = fmaxf(mx, e[s]);
        }
        float den = 0.f;
        for (int s = 0; s < 5; ++s) { e[s] = expf(e[s] - mx); den += e[s]; }
        float inv = 1.f / den;
        for (int s = 0; s < 5; ++s) alpha[dn][s] = e[s] * inv;
    }
    __syncthreads();

    for (int d = tid; d < 512; d += 256) {
        float h0 = bf2f(Hb[0 * 512 + d]), h1 = bf2f(Hb[1 * 512 + d]), h2 = bf2f(Hb[2 * 512 + d]);
        float h3 = bf2f(Hb[3 * 512 + d]), h4 = bf2f(Hb[4 * 512 + d]);
        float bd = bias[d];
#pragma unroll
        for (int dn = 0; dn < 5; ++dn) {
            float v = alpha[dn][0] * h0 + alpha[dn][1] * h1 + alpha[dn][2] * h2 +
                      alpha[dn][3] * h3 + alpha[dn][4] * h4 + bd;
            if (RELU) v = fmaxf(v, 0.f);
            outp[((size_t)b * 5 + dn) * 512 + d] = cvt_bf16(v);
        }
    }
}

// ---------------- final: relu(sum split-K parts + b1) @ m2 + b2 -------------
__global__ __launch_bounds__(64) void final2(
    const float* __restrict__ parts, const float* __restrict__ b1,
    const float* __restrict__ w, const float* __restrict__ bvec,
    float* __restrict__ out)
{
    const int b = blockIdx.x;
    const int lane = threadIdx.x;
    float a0 = 0.f, a1 = 0.f, a2 = 0.f;
#pragma unroll
    for (int j = 0; j < 8; ++j) {
        int d = lane + 64 * j;
        size_t o = (size_t)b * 512 + d;
        float x = parts[o] + parts[262144 + o] + parts[524288 + o] + parts[786432 + o] + b1[d];
        x = fmaxf(x, 0.f);
        a0 += x * w[d * 3 + 0];
        a1 += x * w[d * 3 + 1];
        a2 += x * w[d * 3 + 2];
    }
    for (int off = 32; off > 0; off >>= 1) {
        a0 += __shfl_down(a0, off, 64);
        a1 += __shfl_down(a1, off, 64);
        a2 += __shfl_down(a2, off, 64);
    }
    if (lane == 0) {
        out[b * 3 + 0] = a0 + bvec[0];
        out[b * 3 + 1] = a1 + bvec[1];
        out[b * 3 + 2] = a2 + bvec[2];
    }
}

extern "C" void kernel_launch(void* const* d_in, const int* in_sizes, int n_in,
                              void* d_out, int out_size, void* d_ws, size_t ws_size,
                              hipStream_t stream) {
    const float* text   = (const float*)d_in[0];
    const float* image  = (const float*)d_in[1];
    const float* imgtxt = (const float*)d_in[2];
    const float* face   = (const float*)d_in[3];
    const float* word   = (const float*)d_in[4];
    const float* obj    = (const float*)d_in[5];
    const float* ow_W    = (const float*)d_in[6];
    const float* ow_asrc = (const float*)d_in[7];
    const float* ow_adst = (const float*)d_in[8];
    const float* ow_b    = (const float*)d_in[9];
    const float* g1_W    = (const float*)d_in[10];
    const float* g1_asrc = (const float*)d_in[11];
    const float* g1_adst = (const float*)d_in[12];
    const float* g1_b    = (const float*)d_in[13];
    const float* g2_W    = (const float*)d_in[14];
    const float* g2_asrc = (const float*)d_in[15];
    const float* g2_adst = (const float*)d_in[16];
    const float* g2_b    = (const float*)d_in[17];
    const float* m1_W    = (const float*)d_in[18];
    const float* m1_b    = (const float*)d_in[19];
    const float* m2_W    = (const float*)d_in[20];
    const float* m2_b    = (const float*)d_in[21];

    float* ws = (float*)d_ws;
    float* vg   = ws;                                        // 2048
    float* hidp = ws + 2048;                                 // 1,048,576
    unsigned short* owWt  = (unsigned short*)(hidp + 1048576); // 512x1024
    unsigned short* WsR   = owWt + 524288;                   // 512x512
    unsigned short* g1Wt  = WsR + 262144;                    // 512x544
    unsigned short* g2Wt  = g1Wt + 278528;                   // 512x512
    unsigned short* m1Wt  = g2Wt + 262144;                   // 512x2560
    unsigned short* zw    = m1Wt + 1310720;                  // 8192x1024
    unsigned short* houtW = zw + 8388608;                    // 8192x512
    unsigned short* houtO = houtW + 4194304;                 // 6144x512
    unsigned short* x5b   = houtO + 3145728;                 // 2560x544
    unsigned short* h1b   = x5b + 1392640;                   // 2560x512
    unsigned short* fsb   = h1b + 1310720;                   // 2560x512
    unsigned short* hgb   = fsb + 1310720;                   // 2560x512

    // prep: vg + weight transposes + WsR (sum-halves transpose)
    prep<<<2704, 256, 0, stream>>>(ow_W, ow_asrc, ow_adst, g1_W, g2_W, m1_W,
                                   vg, owWt, g1Wt, g2Wt, m1Wt, WsR);

    // stage A
    ow_zw<<<B_SAMP, 256, 0, stream>>>(word, obj, vg, zw);
    gemm_a1<<<896, 256, 0, stream>>>(zw, owWt, word, WsR, ow_b, houtW, houtO);
    attn_x5<<<B_SAMP, 256, 0, stream>>>(houtO, houtW, text, image, imgtxt, face, x5b);

    // stage C
    gemm_v3<64, 64, 2, 0, 1, 1><<<dim3(40, 8), 256, 0, stream>>>(
        x5b, 544, g1Wt, 544, hgb, 512, 2560, 512, 544, nullptr);
    g5_gat<1><<<B_SAMP, 256, 0, stream>>>(hgb, g1_asrc, g1_adst, g1_b, h1b);
    gemm_v3<64, 64, 2, 0, 1, 1><<<dim3(40, 8), 256, 0, stream>>>(
        h1b, 512, g2Wt, 512, hgb, 512, 2560, 512, 512, nullptr);
    g5_gat<0><<<B_SAMP, 256, 0, stream>>>(hgb, g2_asrc, g2_adst, g2_b, fsb);

    // stage D (fsb viewed as [512][2560])
    gemm_v3<64, 64, 2, 0, 4, 0><<<dim3(8, 8, 4), 256, 0, stream>>>(
        fsb, 2560, m1Wt, 2560, hidp, 512, 512, 512, 2560, nullptr);
    final2<<<B_SAMP, 64, 0, stream>>>(hidp, m1_b, m2_W, m2_b, (float*)d_out);
}